// Round 1
// baseline (110.404 us; speedup 1.0000x reference)
//
#include <hip/hip_runtime.h>
#include <hip/hip_bf16.h>

// Problem constants (from reference setup_inputs):
//   input_data:        (B=16, S=4096, C=256) fp32
//   shifting_weights:  (B=16, D=1024)        fp32
//   output:            (B=16, D=1024, C=256) fp32
// M[b,d,s] = exp(-((s+1) - ((d+1)+w[b,d])*4)^2) / 1.772637204826652
// out[b,d,c] = sum_s M[b,d,s] * input[b,s,c]
// Gaussian band: only |diff| <= 8 contributes above ~1e-28 -> 17-tap window.

constexpr int B = 16;
constexpr int S = 4096;
constexpr int C = 256;
constexpr int D = 1024;
constexpr float SCALING = (float)S / (float)D;   // 4.0
constexpr float INV_AMP = 1.0f / 1.772637204826652f;
constexpr float RADIUS  = 8.0f;

constexpr int G  = 4;                // d's per wave (consecutive centers 4 apart)
constexpr int WPB = 4;               // waves per block
constexpr int DG = G * WPB;          // d's per block = 16
constexpr int C4 = C / 4;            // float4's per row = 64 (== wave width)

__global__ __launch_bounds__(256) void shifting_kernel(
    const float* __restrict__ input,
    const float* __restrict__ wts,
    float* __restrict__ out)
{
    const int wave = threadIdx.x >> 6;
    const int lane = threadIdx.x & 63;
    const int b    = blockIdx.x / (D / DG);
    const int dblk = blockIdx.x % (D / DG);
    const int d0   = dblk * DG + wave * G;   // first (0-based) d of this wave

    // Per-d Gaussian centers (wave-uniform values, computed redundantly per lane)
    float c[G];
#pragma unroll
    for (int i = 0; i < G; ++i) {
        float w = wts[b * D + d0 + i];
        c[i] = ((float)(d0 + i + 1) + w) * SCALING;
    }
    float cmin = fminf(fminf(c[0], c[1]), fminf(c[2], c[3]));
    float cmax = fmaxf(fmaxf(c[0], c[1]), fmaxf(c[2], c[3]));

    // Union window over s in [1, S] (index_input values)
    int s_lo = max(1, (int)ceilf(cmin - RADIUS));
    int s_hi = min(S, (int)floorf(cmax + RADIUS));

    float4 acc[G];
#pragma unroll
    for (int i = 0; i < G; ++i) acc[i] = make_float4(0.f, 0.f, 0.f, 0.f);

    // Lane's float4 within each input row
    const float4* inp = (const float4*)(input + (size_t)b * S * C) + lane;

    for (int s = s_lo; s <= s_hi; ++s) {
        float4 v = inp[(size_t)(s - 1) * C4];
#pragma unroll
        for (int i = 0; i < G; ++i) {
            float diff = (float)s - c[i];
            // Outside its own band this underflows to 0 -> branch-free
            float wgt = __expf(-diff * diff) * INV_AMP;
            acc[i].x = fmaf(wgt, v.x, acc[i].x);
            acc[i].y = fmaf(wgt, v.y, acc[i].y);
            acc[i].z = fmaf(wgt, v.z, acc[i].z);
            acc[i].w = fmaf(wgt, v.w, acc[i].w);
        }
    }

    float4* outp = (float4*)(out + ((size_t)b * D + d0) * C) + lane;
#pragma unroll
    for (int i = 0; i < G; ++i)
        outp[(size_t)i * C4] = acc[i];
}

extern "C" void kernel_launch(void* const* d_in, const int* in_sizes, int n_in,
                              void* d_out, int out_size, void* d_ws, size_t ws_size,
                              hipStream_t stream) {
    const float* input = (const float*)d_in[0];
    const float* wts   = (const float*)d_in[1];
    float* out         = (float*)d_out;

    dim3 grid(B * (D / DG));   // 16 * 64 = 1024 blocks
    dim3 block(WPB * 64);      // 256 threads
    shifting_kernel<<<grid, block, 0, stream>>>(input, wts, out);
}

// Round 2
// 103.829 us; speedup vs baseline: 1.0633x; 1.0633x over previous
//
#include <hip/hip_runtime.h>
#include <hip/hip_bf16.h>

// input_data:       (B=16, S=4096, C=256) fp32
// shifting_weights: (B=16, D=1024)        fp32
// output:           (B=16, D=1024, C=256) fp32
// out[b,d,c] = sum_s exp(-((s+1) - ((d+1)+w[b,d])*4)^2) / AMP * input[b,s,c]
// Gaussian with width 1: taps beyond |diff| > 8.5 are < 4e-32 -> fixed 17-tap
// window centered at round(center). Fully unrolled so all 17 independent
// global_load_dwordx4 issue with staggered vmcnt (MLP), instead of the R1
// dynamic loop's serialized load->waitcnt(0)->fma pattern.

constexpr int B = 16;
constexpr int S = 4096;
constexpr int C = 256;
constexpr int D = 1024;
constexpr float SCALING = (float)S / (float)D;   // 4.0
constexpr float INV_AMP = 1.0f / 1.772637204826652f;
constexpr int RAD  = 8;
constexpr int TAPS = 2 * RAD + 1;                // 17

__global__ __launch_bounds__(256) void shifting_kernel(
    const float* __restrict__ input,
    const float* __restrict__ wts,
    float* __restrict__ out)
{
    const int wave = threadIdx.x >> 6;
    const int lane = threadIdx.x & 63;
    const int gidx = (blockIdx.x << 2) + wave;   // flat b*D + d, one d per wave
    const int b    = gidx >> 10;                 // / D
    const int d    = gidx & (D - 1);

    const float w = wts[gidx];
    const float c = ((float)(d + 1) + w) * SCALING;
    const int s_mid = (int)rintf(c);
    const int s0    = s_mid - RAD;               // first tap (1-based s index)

    const float* rowbase = input + ((size_t)b * S * C) + (lane << 2);

    float4 acc = make_float4(0.f, 0.f, 0.f, 0.f);

    if (s0 >= 1 && s0 + TAPS - 1 <= S) {
        // Interior fast path: no clamping, 17 independent loads.
        const float* p = rowbase + (size_t)(s0 - 1) * C;
#pragma unroll
        for (int k = 0; k < TAPS; ++k) {
            float4 v = *(const float4*)(p + (size_t)k * C);
            float diff = (float)(s0 + k) - c;
            float g = __expf(-diff * diff) * INV_AMP;
            acc.x = fmaf(g, v.x, acc.x);
            acc.y = fmaf(g, v.y, acc.y);
            acc.z = fmaf(g, v.z, acc.z);
            acc.w = fmaf(g, v.w, acc.w);
        }
    } else {
        // Edge path (rare): clamp address, zero out-of-range weights.
#pragma unroll
        for (int k = 0; k < TAPS; ++k) {
            int s  = s0 + k;
            int sc = min(max(s, 1), S);
            float4 v = *(const float4*)(rowbase + (size_t)(sc - 1) * C);
            float diff = (float)s - c;
            float g = __expf(-diff * diff) * INV_AMP;
            g = (s >= 1 && s <= S) ? g : 0.0f;
            acc.x = fmaf(g, v.x, acc.x);
            acc.y = fmaf(g, v.y, acc.y);
            acc.z = fmaf(g, v.z, acc.z);
            acc.w = fmaf(g, v.w, acc.w);
        }
    }

    *(float4*)(out + (size_t)gidx * C + (lane << 2)) = acc;
}

extern "C" void kernel_launch(void* const* d_in, const int* in_sizes, int n_in,
                              void* d_out, int out_size, void* d_ws, size_t ws_size,
                              hipStream_t stream) {
    const float* input = (const float*)d_in[0];
    const float* wts   = (const float*)d_in[1];
    float* out         = (float*)d_out;

    dim3 grid(B * D / 4);   // 4096 blocks, 4 waves/block, 1 d per wave
    dim3 block(256);
    shifting_kernel<<<grid, block, 0, stream>>>(input, wts, out);
}

// Round 3
// 97.273 us; speedup vs baseline: 1.1350x; 1.0674x over previous
//
#include <hip/hip_runtime.h>
#include <hip/hip_bf16.h>

// input_data:       (B=16, S=4096, C=256) fp32
// shifting_weights: (B=16, D=1024)        fp32
// output:           (B=16, D=1024, C=256) fp32
// out[b,d,c] = sum_s exp(-((s+1) - ((d+1)+w[b,d])*4)^2) / AMP * input[b,s,c]
// Gaussian width 1: 17-tap window centered at round(center); taps beyond
// |diff| > 8.5 are < 4e-32.
//
// R3 changes vs R2:
//  * XCD swizzle: hardware assigns block -> XCD round-robin (blockIdx % 8),
//    which scatters overlapping-window d's across XCDs (zero L2 locality; all
//    reuse falls to L3/HBM). Remap so each XCD owns a CONTIGUOUS gidx range:
//    its 17-row sliding window then stays resident in its 4 MiB L2.
//  * Non-temporal output stores: output is write-once, keep it from evicting
//    input lines in L2/L3.

constexpr int B = 16;
constexpr int S = 4096;
constexpr int C = 256;
constexpr int D = 1024;
constexpr float SCALING = (float)S / (float)D;   // 4.0
constexpr float INV_AMP = 1.0f / 1.772637204826652f;
constexpr int RAD  = 8;
constexpr int TAPS = 2 * RAD + 1;                // 17
constexpr int NUM_XCD = 8;

typedef float f32x4 __attribute__((ext_vector_type(4)));

__global__ __launch_bounds__(256) void shifting_kernel(
    const float* __restrict__ input,
    const float* __restrict__ wts,
    float* __restrict__ out)
{
    const int wave = threadIdx.x >> 6;
    const int lane = threadIdx.x & 63;

    // --- XCD-contiguity swizzle (bijection on [0, gridDim.x)) ---
    // physical block p runs on XCD (p % 8); give XCD x the logical range
    // [x*per_xcd, (x+1)*per_xcd) so its L2 sees a contiguous d-span.
    const int per_xcd = gridDim.x >> 3;              // 4096/8 = 512
    const int pblk = blockIdx.x;
    const int lblk = (pblk & (NUM_XCD - 1)) * per_xcd + (pblk >> 3);

    const int gidx = (lblk << 2) + wave;             // flat b*D + d
    const int b    = gidx >> 10;                     // / D
    const int d    = gidx & (D - 1);

    const float w = wts[gidx];
    const float c = ((float)(d + 1) + w) * SCALING;
    const int s_mid = (int)rintf(c);
    const int s0    = s_mid - RAD;                   // first tap (1-based s)

    const float* rowbase = input + ((size_t)b * S * C) + (lane << 2);

    f32x4 acc = {0.f, 0.f, 0.f, 0.f};

    if (s0 >= 1 && s0 + TAPS - 1 <= S) {
        // Interior fast path: 17 independent 1 KB wave-loads.
        const float* p = rowbase + (size_t)(s0 - 1) * C;
#pragma unroll
        for (int k = 0; k < TAPS; ++k) {
            f32x4 v = *(const f32x4*)(p + (size_t)k * C);
            float diff = (float)(s0 + k) - c;
            float g = __expf(-diff * diff) * INV_AMP;
            acc += g * v;
        }
    } else {
        // Edge path (rare): clamp address, zero out-of-range weights.
#pragma unroll
        for (int k = 0; k < TAPS; ++k) {
            int s  = s0 + k;
            int sc = min(max(s, 1), S);
            f32x4 v = *(const f32x4*)(rowbase + (size_t)(sc - 1) * C);
            float diff = (float)s - c;
            float g = __expf(-diff * diff) * INV_AMP;
            g = (s >= 1 && s <= S) ? g : 0.0f;
            acc += g * v;
        }
    }

    // Write-once output: non-temporal so it doesn't evict cached input.
    f32x4* outp = (f32x4*)(out + (size_t)gidx * C + (lane << 2));
    __builtin_nontemporal_store(acc, outp);
}

extern "C" void kernel_launch(void* const* d_in, const int* in_sizes, int n_in,
                              void* d_out, int out_size, void* d_ws, size_t ws_size,
                              hipStream_t stream) {
    const float* input = (const float*)d_in[0];
    const float* wts   = (const float*)d_in[1];
    float* out         = (float*)d_out;

    dim3 grid(B * D / 4);   // 4096 blocks, 4 waves/block, 1 d per wave
    dim3 block(256);
    shifting_kernel<<<grid, block, 0, stream>>>(input, wts, out);
}